// Round 16
// baseline (1182.502 us; speedup 1.0000x reference)
//
#include <hip/hip_runtime.h>
#include <hip/hip_bf16.h>
#include <math.h>

#define C_DIM 256
#define N_EMB 8192
#define N_Z   8192
#define HWB   1024
#define MBLK  128                 // z rows per filter block (4 waves x 32, row-disjoint)
#define NSPLIT 8                  // e splits; ns=bid&7 -> one 0.5MB split per XCD
#define SPLITC (N_EMB / NSPLIT)   // 1024 cols per split
#define NT    64                  // e cols per tile (full K staged: 64c x 256k = 32 KB)
#define NTILES (SPLITC / NT)      // 16 steps
#define CK    12                  // candidate slots per row (tail only)
#define EPS   1.1e-3f             // >= 2*hard bound |u_exact - u_approx| (~5e-4)
#define ZQ_ELEMS (N_Z * C_DIM)

typedef __attribute__((ext_vector_type(8))) short bf16x8;
typedef __attribute__((ext_vector_type(4))) float f32x4;
typedef unsigned short u16;
typedef unsigned int u32;

__device__ __forceinline__ float sqf(float x) { return __fmul_rn(x, x); }

__device__ __forceinline__ u16 f2bf(float v) {
  __hip_bfloat16 h = __float2bfloat16(v);
  u16 r; __builtin_memcpy(&r, &h, 2); return r;
}

// async global->LDS, 16B/lane; LDS dest = wave-uniform base + lane*16
__device__ __forceinline__ void g2l16(const u16* g, u16* l) {
  __builtin_amdgcn_global_load_lds(
      (const __attribute__((address_space(1))) unsigned int*)(const void*)g,
      (__attribute__((address_space(3))) unsigned int*)(void*)l, 16, 0, 0);
}

// Exact replication of numpy pairwise summation of 256 squared elements.
template <int STRIDE>
__device__ float pw_sumsq_256(const float* __restrict__ a) {
  float h[2];
#pragma unroll
  for (int hh = 0; hh < 2; ++hh) {
    const float* p = a + hh * 128 * STRIDE;
    float r0 = sqf(p[0 * STRIDE]), r1 = sqf(p[1 * STRIDE]);
    float r2 = sqf(p[2 * STRIDE]), r3 = sqf(p[3 * STRIDE]);
    float r4 = sqf(p[4 * STRIDE]), r5 = sqf(p[5 * STRIDE]);
    float r6 = sqf(p[6 * STRIDE]), r7 = sqf(p[7 * STRIDE]);
    for (int i = 8; i < 128; i += 8) {
      r0 = __fadd_rn(r0, sqf(p[(i + 0) * STRIDE]));
      r1 = __fadd_rn(r1, sqf(p[(i + 1) * STRIDE]));
      r2 = __fadd_rn(r2, sqf(p[(i + 2) * STRIDE]));
      r3 = __fadd_rn(r3, sqf(p[(i + 3) * STRIDE]));
      r4 = __fadd_rn(r4, sqf(p[(i + 4) * STRIDE]));
      r5 = __fadd_rn(r5, sqf(p[(i + 5) * STRIDE]));
      r6 = __fadd_rn(r6, sqf(p[(i + 6) * STRIDE]));
      r7 = __fadd_rn(r7, sqf(p[(i + 7) * STRIDE]));
    }
    h[hh] = __fadd_rn(__fadd_rn(__fadd_rn(r0, r1), __fadd_rn(r2, r3)),
                      __fadd_rn(__fadd_rn(r4, r5), __fadd_rn(r6, r7)));
  }
  return __fadd_rn(h[0], h[1]);
}

// exact sequential dot (k = 0..255 ascending, xyzw) -- identical op order to
// the verified exact path of rounds 1-15.
__device__ __forceinline__ float exact_score(const float* __restrict__ zr,
                                             const float* __restrict__ er,
                                             float z2v, float e2v) {
  float d = 0.f;
  for (int k4 = 0; k4 < 64; ++k4) {
    float4 a4 = *(const float4*)(zr + k4 * 4);
    float4 b4 = *(const float4*)(er + k4 * 4);
    d = fmaf(a4.x, b4.x, d); d = fmaf(a4.y, b4.y, d);
    d = fmaf(a4.z, b4.z, d); d = fmaf(a4.w, b4.w, d);
  }
  return __fsub_rn(__fadd_rn(z2v, e2v), __fmul_rn(2.f, d));
}

// branchless sorted top-3 insert (strict <; cols visited ascending per lane
// -> lowest col kept on ties). Verified in R14 (absmax 0).
__device__ __forceinline__ void top3_ins(float s, int c,
                                         float& v0, float& v1, float& v2,
                                         int& i0, int& i1, int& i2) {
  bool b2 = s < v2, b1 = s < v1, b0 = s < v0;
  v2 = b1 ? v1 : (b2 ? s : v2);  i2 = b1 ? i1 : (b2 ? c : i2);
  v1 = b0 ? v0 : (b1 ? s : v1);  i1 = b0 ? i0 : (b1 ? c : i1);
  v0 = b0 ? s : v0;              i0 = b0 ? c : i0;
}

// Transpose hid [b][c][hw] -> zt fp32 [n][c] and zbf bf16 [n][c].
__global__ void vq_tr(const float* __restrict__ hid, float* __restrict__ zt,
                      u16* __restrict__ zbf) {
  __shared__ float tl[32][33];
  int t = threadIdx.x;
  int tx = t & 31, ty = t >> 5;
  int bb = blockIdx.x >> 8;
  int r = blockIdx.x & 255;
  int cT = r >> 5, hwT = r & 31;
#pragma unroll
  for (int p = 0; p < 4; ++p)
    tl[ty + p * 8][tx] =
        hid[((size_t)bb * C_DIM + cT * 32 + ty + p * 8) * HWB + hwT * 32 + tx];
  __syncthreads();
#pragma unroll
  for (int p = 0; p < 4; ++p) {
    float v = tl[tx][ty + p * 8];
    size_t oi = ((size_t)bb * HWB + hwT * 32 + ty + p * 8) * C_DIM + cT * 32 + tx;
    zt[oi] = v;
    zbf[oi] = f2bf(v);
  }
}

// blocks 0..31: e2 + ebf; blocks 32..63: z2 (from zt)
__global__ void vq_norms(const float* __restrict__ zt, const float* __restrict__ emb,
                         float* __restrict__ z2, float* __restrict__ e2,
                         u16* __restrict__ ebf) {
  int t = threadIdx.x, b = blockIdx.x;
  if (b < 32) {
    int r = b * 256 + t;
    e2[r] = pw_sumsq_256<1>(emb + (size_t)r * C_DIM);
    for (int k4 = 0; k4 < 64; ++k4) {
      float4 v = *(const float4*)(emb + (size_t)r * C_DIM + k4 * 4);
      ushort4 o;
      o.x = f2bf(v.x); o.y = f2bf(v.y); o.z = f2bf(v.z); o.w = f2bf(v.w);
      *(ushort4*)(ebf + (size_t)r * C_DIM + k4 * 4) = o;
    }
  } else {
    int n = (b - 32) * 256 + t;
    z2[n] = pw_sumsq_256<1>(zt + (size_t)n * C_DIM);
  }
}

// Single-pass MFMA filter, staged-bytes minimized.
// Cross-round model (R8-R15): per-CU cost ~= staged_bytes / ~9 B/cyc,
// invariant to pass count, co-residency, and wait scheme. R15 staged 1 GB
// (two passes, SPLITC=2048) -> 190us. This kernel stages 256 MB:
// single pass + NSPLIT=8 + full-K 32KB tiles (64c x 256k), 16 steps/block.
// Block: 256 thr = 4 ROW-DISJOINT waves (wave w -> rows w*32..+31, all 64
// tile cols). z (A) in registers; e DMA-staged into el[2] double buffer
// (R15's proven stage->compute->barrier pattern). Filter: per-lane top-3 of
// u = e2 - 2*dot (z2 row-constant, drops out of argmin) -- R14-verified.
// Tail: per-row window thr = min+EPS; in-window cols -> per-row LDS lists;
// suspect rows (some lane's 3rd-best in window, or list overflow) -> exact
// full-split scan. All reported scores from the bit-exact path.
__global__ __launch_bounds__(256) void vq_filter(
    const u16* __restrict__ zbf, const u16* __restrict__ ebf,
    const float* __restrict__ zt, const float* __restrict__ emb,
    const float* __restrict__ z2g, const float* __restrict__ e2g,
    float* __restrict__ cd, int* __restrict__ ci) {
  __shared__ u16 el[2][16384];        // 64 KB: 2 bufs x (64 cols x 256 k)
  __shared__ u16 rcol[MBLK * CK];     // 3 KB
  __shared__ int rcnt[MBLK];
  __shared__ int sus[MBLK];
  __shared__ int ovfr[MBLK];
  __shared__ int novf;
  __shared__ float wbs[4];
  __shared__ int wis[4];

  int t = threadIdx.x;
  int mb = blockIdx.x >> 3;           // 0..63
  int ns = blockIdx.x & 7;            // XCD-local split
  int n0z = mb * MBLK;
  int l = t & 63;
  int w = t >> 6;                     // wave id -> rows w*32..w*32+31
  int x = l & 15, hi = l >> 4;

  if (t < MBLK) { rcnt[t] = 0; sus[t] = 0; }
  if (t == 0) novf = 0;

  // A fragments: rows n0z + w*32 + rf*16 + x, k = kf*32 + hi*8
  bf16x8 A[2][8];
#pragma unroll
  for (int rf = 0; rf < 2; ++rf)
#pragma unroll
    for (int kf = 0; kf < 8; ++kf)
      A[rf][kf] = *(const bf16x8*)(zbf +
          (size_t)(n0z + w * 32 + rf * 16 + x) * C_DIM + kf * 32 + hi * 8);

  float v0[2][4], v1[2][4], v2[2][4];
  int i0[2][4], i1[2][4], i2[2][4];
#pragma unroll
  for (int rf = 0; rf < 2; ++rf)
#pragma unroll
    for (int r = 0; r < 4; ++r) {
      v0[rf][r] = INFINITY; v1[rf][r] = INFINITY; v2[rf][r] = INFINITY;
      i0[rf][r] = N_EMB; i1[rf][r] = N_EMB; i2[rf][r] = N_EMB;
    }

  const f32x4 vzero = {0.f, 0.f, 0.f, 0.f};
  const u16* esplit = ebf + (size_t)(ns * SPLITC) * C_DIM;

  // stage full-K tile tn_ (64 cols x 256 k = 32 KB) into buffer nb_.
  // LDS: col-major, 512 B/col = 32 x 16B slots; logical slot s stored at
  // phys s ^ (col&15) (bijective; read pattern lands conflict-free).
  // Source pre-swizzled, LDS dest linear (wave-uniform base + lane*16).
#define STAGE_E(nb_, tn_)                                                     \
  {                                                                           \
    const u16* bs_ = esplit + (size_t)((tn_) * NT) * C_DIM;                   \
    _Pragma("unroll")                                                         \
    for (int p_ = 0; p_ < 8; ++p_) {                                          \
      int j_ = (w * 8 + p_) * 64 + l;      /* 16B-slot id 0..2047 */          \
      int col_ = j_ >> 5, sp_ = j_ & 31;                                      \
      int slog_ = sp_ ^ (col_ & 15);                                          \
      g2l16(bs_ + (size_t)col_ * C_DIM + slog_ * 8,                           \
            &el[nb_][(w * 8 + p_) * 512]);                                    \
    }                                                                         \
  }

  STAGE_E(0, 0)
  __syncthreads();   // drains tile-0 DMA + LDS init

  int cur = 0;
#pragma unroll 1
  for (int tile = 0; tile < NTILES; ++tile) {
    if (tile + 1 < NTILES) STAGE_E(cur ^ 1, tile + 1)

    f32x4 acc[2][4];
#pragma unroll
    for (int rf = 0; rf < 2; ++rf)
#pragma unroll
      for (int cf = 0; cf < 4; ++cf) acc[rf][cf] = vzero;

#pragma unroll
    for (int kf = 0; kf < 8; ++kf) {
      int sp = (kf * 4 + hi) ^ x;        // phys 16B slot
#pragma unroll
      for (int cf = 0; cf < 4; ++cf) {
        int col = cf * 16 + x;
        bf16x8 B = *(const bf16x8*)(&el[cur][col * 256 + sp * 8]);
        acc[0][cf] = __builtin_amdgcn_mfma_f32_16x16x32_bf16(A[0][kf], B, acc[0][cf], 0, 0, 0);
        acc[1][cf] = __builtin_amdgcn_mfma_f32_16x16x32_bf16(A[1][kf], B, acc[1][cf], 0, 0, 0);
      }
    }
    // epilogue: u = e2 - 2*dot; per-lane top-3 (registers only)
    {
      int ne0 = ns * SPLITC + tile * NT;
      float e2s[4];
#pragma unroll
      for (int cf = 0; cf < 4; ++cf)
        e2s[cf] = e2g[ne0 + cf * 16 + x];
#pragma unroll
      for (int rf = 0; rf < 2; ++rf)
#pragma unroll
        for (int r = 0; r < 4; ++r)
#pragma unroll
          for (int cf = 0; cf < 4; ++cf) {
            float u = fmaf(-2.f, acc[rf][cf][r], e2s[cf]);
            top3_ins(u, ne0 + cf * 16 + x,
                     v0[rf][r], v1[rf][r], v2[rf][r],
                     i0[rf][r], i1[rf][r], i2[rf][r]);
          }
    }
    __syncthreads();   // drains next-tile DMA + this buffer's reads
    cur ^= 1;
  }

  // tail: windows, suspects, candidate lists (tail-only atomics)
#pragma unroll
  for (int rf = 0; rf < 2; ++rf)
#pragma unroll
    for (int r = 0; r < 4; ++r) {
      int rowl = w * 32 + rf * 16 + hi * 4 + r;
      float m = v0[rf][r];
#pragma unroll
      for (int mk = 1; mk <= 8; mk <<= 1) m = fminf(m, __shfl_xor(m, mk, 64));
      float thr = m + EPS;
      if (v2[rf][r] <= thr) atomicOr(&sus[rowl], 1);
      if (v0[rf][r] <= thr) {
        int pos = atomicAdd(&rcnt[rowl], 1);
        if (pos < CK) rcol[rowl * CK + pos] = (u16)i0[rf][r];
      }
      if (v1[rf][r] <= thr) {
        int pos = atomicAdd(&rcnt[rowl], 1);
        if (pos < CK) rcol[rowl * CK + pos] = (u16)i1[rf][r];
      }
      if (v2[rf][r] <= thr) {
        int pos = atomicAdd(&rcnt[rowl], 1);
        if (pos < CK) rcol[rowl * CK + pos] = (u16)i2[rf][r];
      }
    }
  __syncthreads();

  // exact rescreen: 2 threads per row over that row's candidate list
  {
    int row = t >> 1;
    int cnt = rcnt[row];
    bool ok = (sus[row] == 0) && (cnt <= CK);
    float b = INFINITY; int bi = N_EMB;
    if (ok) {
      const float* zr = zt + (size_t)(n0z + row) * C_DIM;
      float z2v = z2g[n0z + row];
      for (int p2 = (t & 1); p2 < cnt; p2 += 2) {
        int col = rcol[row * CK + p2];
        float s = exact_score(zr, emb + (size_t)col * C_DIM, z2v, e2g[col]);
        if (s < b || (s == b && col < bi)) { b = s; bi = col; }
      }
      float ob = __shfl_xor(b, 1, 64);
      int oi2 = __shfl_xor(bi, 1, 64);
      if (ob < b || (ob == b && oi2 < bi)) { b = ob; bi = oi2; }
      if ((t & 1) == 0) {
        cd[ns * N_Z + n0z + row] = b;
        ci[ns * N_Z + n0z + row] = bi;
      }
    } else if ((t & 1) == 0) {
      int p = atomicAdd(&novf, 1);
      ovfr[p] = row;
    }
  }
  __syncthreads();

  // fallback: exact full-split scan for suspect/overflowed rows
  int no = novf;
  for (int oi = 0; oi < no; ++oi) {
    int row = ovfr[oi];
    const float* zr = zt + (size_t)(n0z + row) * C_DIM;
    float z2v = z2g[n0z + row];
    float b = INFINITY; int bi = N_EMB;
#pragma unroll
    for (int q = 0; q < 4; ++q) {
      int col = ns * SPLITC + t * 4 + q;
      float s = exact_score(zr, emb + (size_t)col * C_DIM, z2v, e2g[col]);
      if (s < b || (s == b && col < bi)) { b = s; bi = col; }
    }
#pragma unroll
    for (int mk = 1; mk <= 32; mk <<= 1) {
      float ob = __shfl_xor(b, mk, 64);
      int oi2 = __shfl_xor(bi, mk, 64);
      if (ob < b || (ob == b && oi2 < bi)) { b = ob; bi = oi2; }
    }
    if (l == 0) { wbs[w] = b; wis[w] = bi; }
    __syncthreads();
    if (t == 0) {
      for (int w2 = 1; w2 < 4; ++w2)
        if (wbs[w2] < b || (wbs[w2] == b && wis[w2] < bi)) { b = wbs[w2]; bi = wis[w2]; }
      cd[ns * N_Z + n0z + row] = b;
      ci[ns * N_Z + n0z + row] = bi;
    }
    __syncthreads();
  }
}

// merge NSPLIT candidates per row, write indices (as float) and gather z_q
__global__ void vq_out(const float* __restrict__ emb, const float* __restrict__ cd,
                       const int* __restrict__ ci, float* __restrict__ out) {
  __shared__ int sidx[32];
  int t = threadIdx.x;
  int n0 = blockIdx.x * 32;
  if (t < 32) {
    int n = n0 + t;
    float b = INFINITY;
    int bi = 0;
    for (int ns = 0; ns < NSPLIT; ++ns) {        // ascending split = ascending idx
      float d = cd[ns * N_Z + n];
      int i = ci[ns * N_Z + n];
      if (d < b || (d == b && i < bi)) { b = d; bi = i; }
    }
    sidx[t] = bi;
    out[ZQ_ELEMS + n] = (float)bi;
  }
  __syncthreads();
  int bb = n0 >> 10, hw0 = n0 & 1023;
  int nl = t & 31, cg = t >> 5;
#pragma unroll
  for (int p = 0; p < 8; ++p) {
    int c0 = cg * 4 + p * 32;
    float4 v = *(const float4*)(emb + (size_t)sidx[nl] * C_DIM + c0);
    out[((size_t)bb * C_DIM + c0 + 0) * HWB + hw0 + nl] = v.x;
    out[((size_t)bb * C_DIM + c0 + 1) * HWB + hw0 + nl] = v.y;
    out[((size_t)bb * C_DIM + c0 + 2) * HWB + hw0 + nl] = v.z;
    out[((size_t)bb * C_DIM + c0 + 3) * HWB + hw0 + nl] = v.w;
  }
}

extern "C" void kernel_launch(void* const* d_in, const int* in_sizes, int n_in,
                              void* d_out, int out_size, void* d_ws, size_t ws_size,
                              hipStream_t stream) {
  const float* hid = (const float*)d_in[0];
  const float* emb = (const float*)d_in[1];
  float* out = (float*)d_out;

  float* zt = (float*)d_ws;                        // 8 MB
  float* z2 = zt + (size_t)N_Z * C_DIM;            // 8192
  float* e2 = z2 + N_Z;                            // 8192
  float* cd = e2 + N_EMB;                          // NSPLIT*8192
  int* ci = (int*)(cd + (size_t)NSPLIT * N_Z);     // NSPLIT*8192
  u16* zbf = (u16*)(ci + (size_t)NSPLIT * N_Z);    // 4 MB
  u16* ebf = zbf + (size_t)N_Z * C_DIM;            // 4 MB

  vq_tr<<<2048, 256, 0, stream>>>(hid, zt, zbf);
  vq_norms<<<64, 256, 0, stream>>>(zt, emb, z2, e2, ebf);
  vq_filter<<<(N_Z / MBLK) * NSPLIT, 256, 0, stream>>>(zbf, ebf, zt, emb, z2, e2, cd, ci);
  vq_out<<<N_Z / 32, 256, 0, stream>>>(emb, cd, ci, out);
}

// Round 17
// 252.944 us; speedup vs baseline: 4.6749x; 4.6749x over previous
//
#include <hip/hip_runtime.h>
#include <hip/hip_bf16.h>
#include <math.h>

#define C_DIM 256
#define N_EMB 8192
#define N_Z   8192
#define HWB   1024
#define MBLK  256                 // z rows per filter block (8 row-disjoint waves x 32)
#define NSPLIT 8                  // e splits; ns=bid&7 -> one 0.5MB split per XCD
#define SPLITC (N_EMB / NSPLIT)   // 1024 cols per split
#define NT    64                  // e cols per tile
#define NTILES (SPLITC / NT)      // 16
#define NCHUNK (NTILES * 2)       // 32 chunks (64 cols x 128 k = 16 KB) per pass
#define CK    32                  // candidate slots per row
#define EPS   1.1e-3f             // >= 2*hard bound on |s_exact - s_approx| (~7.8e-4)
#define ZQ_ELEMS (N_Z * C_DIM)

typedef __attribute__((ext_vector_type(8))) short bf16x8;
typedef __attribute__((ext_vector_type(4))) float f32x4;
typedef unsigned short u16;
typedef unsigned int u32;

__device__ __forceinline__ float sqf(float x) { return __fmul_rn(x, x); }

__device__ __forceinline__ u16 f2bf(float v) {
  __hip_bfloat16 h = __float2bfloat16(v);
  u16 r; __builtin_memcpy(&r, &h, 2); return r;
}

// async global->LDS, 16B per lane; LDS dest = wave-uniform base + lane*16
__device__ __forceinline__ void g2l16(const u16* g, u16* l) {
  __builtin_amdgcn_global_load_lds(
      (const __attribute__((address_space(1))) unsigned int*)(const void*)g,
      (__attribute__((address_space(3))) unsigned int*)(void*)l, 16, 0, 0);
}

// Exact replication of numpy pairwise summation of 256 squared elements.
template <int STRIDE>
__device__ float pw_sumsq_256(const float* __restrict__ a) {
  float h[2];
#pragma unroll
  for (int hh = 0; hh < 2; ++hh) {
    const float* p = a + hh * 128 * STRIDE;
    float r0 = sqf(p[0 * STRIDE]), r1 = sqf(p[1 * STRIDE]);
    float r2 = sqf(p[2 * STRIDE]), r3 = sqf(p[3 * STRIDE]);
    float r4 = sqf(p[4 * STRIDE]), r5 = sqf(p[5 * STRIDE]);
    float r6 = sqf(p[6 * STRIDE]), r7 = sqf(p[7 * STRIDE]);
    for (int i = 8; i < 128; i += 8) {
      r0 = __fadd_rn(r0, sqf(p[(i + 0) * STRIDE]));
      r1 = __fadd_rn(r1, sqf(p[(i + 1) * STRIDE]));
      r2 = __fadd_rn(r2, sqf(p[(i + 2) * STRIDE]));
      r3 = __fadd_rn(r3, sqf(p[(i + 3) * STRIDE]));
      r4 = __fadd_rn(r4, sqf(p[(i + 4) * STRIDE]));
      r5 = __fadd_rn(r5, sqf(p[(i + 5) * STRIDE]));
      r6 = __fadd_rn(r6, sqf(p[(i + 6) * STRIDE]));
      r7 = __fadd_rn(r7, sqf(p[(i + 7) * STRIDE]));
    }
    h[hh] = __fadd_rn(__fadd_rn(__fadd_rn(r0, r1), __fadd_rn(r2, r3)),
                      __fadd_rn(__fadd_rn(r4, r5), __fadd_rn(r6, r7)));
  }
  return __fadd_rn(h[0], h[1]);
}

// exact sequential dot (k = 0..255 ascending, xyzw) -- identical op order to
// the verified exact path of rounds 1-15.
__device__ __forceinline__ float exact_score(const float* __restrict__ zr,
                                             const float* __restrict__ er,
                                             float z2v, float e2v) {
  float d = 0.f;
  for (int k4 = 0; k4 < 64; ++k4) {
    float4 a4 = *(const float4*)(zr + k4 * 4);
    float4 b4 = *(const float4*)(er + k4 * 4);
    d = fmaf(a4.x, b4.x, d); d = fmaf(a4.y, b4.y, d);
    d = fmaf(a4.z, b4.z, d); d = fmaf(a4.w, b4.w, d);
  }
  return __fsub_rn(__fadd_rn(z2v, e2v), __fmul_rn(2.f, d));
}

// Transpose hid [b][c][hw] -> zt fp32 [n][c] and zbf bf16 [n][c].
__global__ void vq_tr(const float* __restrict__ hid, float* __restrict__ zt,
                      u16* __restrict__ zbf) {
  __shared__ float tl[32][33];
  int t = threadIdx.x;
  int tx = t & 31, ty = t >> 5;
  int bb = blockIdx.x >> 8;
  int r = blockIdx.x & 255;
  int cT = r >> 5, hwT = r & 31;
#pragma unroll
  for (int p = 0; p < 4; ++p)
    tl[ty + p * 8][tx] =
        hid[((size_t)bb * C_DIM + cT * 32 + ty + p * 8) * HWB + hwT * 32 + tx];
  __syncthreads();
#pragma unroll
  for (int p = 0; p < 4; ++p) {
    float v = tl[tx][ty + p * 8];
    size_t oi = ((size_t)bb * HWB + hwT * 32 + ty + p * 8) * C_DIM + cT * 32 + tx;
    zt[oi] = v;
    zbf[oi] = f2bf(v);
  }
}

// blocks 0..31: e2 + ebf; blocks 32..63: z2 (from zt)
__global__ void vq_norms(const float* __restrict__ zt, const float* __restrict__ emb,
                         float* __restrict__ z2, float* __restrict__ e2,
                         u16* __restrict__ ebf) {
  int t = threadIdx.x, b = blockIdx.x;
  if (b < 32) {
    int r = b * 256 + t;
    e2[r] = pw_sumsq_256<1>(emb + (size_t)r * C_DIM);
    for (int k4 = 0; k4 < 64; ++k4) {
      float4 v = *(const float4*)(emb + (size_t)r * C_DIM + k4 * 4);
      ushort4 o;
      o.x = f2bf(v.x); o.y = f2bf(v.y); o.z = f2bf(v.z); o.w = f2bf(v.w);
      *(ushort4*)(ebf + (size_t)r * C_DIM + k4 * 4) = o;
    }
  } else {
    int n = (b - 32) * 256 + t;
    z2[n] = pw_sumsq_256<1>(zt + (size_t)n * C_DIM);
  }
}

// Two-pass MFMA filter + exact rescreen -- R15 (verified, 192us) with ONE
// structural variable changed: wave grid 4x2 -> 8x1. Each staged e-byte now
// serves 256 z-rows instead of 128, and NSPLIT 4->8 halves the split, so
// total staged bytes drop 1 GB -> 256 MB (the R8-R15 cost model's term).
// Per-wave register structure, DMA macro shape, swizzles, two-pass logic,
// rescreen and fallback are IDENTICAL to R15. Grid 256 = 1 block/CU
// (R15 proved co-residency is not the lever).
__global__ __launch_bounds__(512, 2) void vq_filter(
    const u16* __restrict__ zbf, const u16* __restrict__ ebf,
    const float* __restrict__ zt, const float* __restrict__ emb,
    const float* __restrict__ z2g, const float* __restrict__ e2g,
    float* __restrict__ cd, int* __restrict__ ci) {
  __shared__ u16 el[2][8192];         // 32 KB: 2 bufs x (64 cols x 128 k)
  __shared__ u32 mrow[MBLK];          // float bits of row min (1 KB)
  __shared__ u16 rcol[MBLK * CK];     // 16 KB
  __shared__ int rcnt[MBLK];          // 1 KB
  __shared__ int ovfr[32];
  __shared__ int novf;
  __shared__ float wbs[8];
  __shared__ int wis[8];

  int t = threadIdx.x;
  int mb = blockIdx.x >> 3;           // 0..31
  int ns = blockIdx.x & 7;            // XCD-local 0.5 MB split
  int n0z = mb * MBLK;
  int l = t & 63;
  int w = t >> 6;                     // 8 row-waves: rows w*32 .. w*32+31
  int x = l & 15, hi = l >> 4;

  if (t < MBLK) { rcnt[t] = 0; mrow[t] = 0x7f800000u; }
  if (t == 0) novf = 0;

  // A fragments in registers: rows n0z + w*32 + rf*16 + x,
  // k = f*32 + hi*8  (same lane->k map as the B LDS reads; 64 VGPR).
  bf16x8 A[2][8];
#pragma unroll
  for (int rf = 0; rf < 2; ++rf)
#pragma unroll
    for (int f = 0; f < 8; ++f)
      A[rf][f] = *(const bf16x8*)(zbf +
          (size_t)(n0z + w * 32 + rf * 16 + x) * C_DIM + f * 32 + hi * 8);

  float z2r[2][4];
#pragma unroll
  for (int rf = 0; rf < 2; ++rf)
#pragma unroll
    for (int r = 0; r < 4; ++r)
      z2r[rf][r] = z2g[n0z + w * 32 + rf * 16 + hi * 4 + r];

  float mpl[2][4];
#pragma unroll
  for (int rf = 0; rf < 2; ++rf)
#pragma unroll
    for (int r = 0; r < 4; ++r) mpl[rf][r] = INFINITY;

  const f32x4 vzero = {0.f, 0.f, 0.f, 0.f};
  const u16* esplit = ebf + (size_t)(ns * SPLITC) * C_DIM;

  // stage chunk c (tile c>>1, k-half c&1; 64 cols x 128 k = 16 KB) into buf
  // nb: 2 DMA/wave. Linear LDS dest; source pre-swizzled (slot ^ (col&7)).
#define STAGE_E(nb_, c_)                                                      \
  {                                                                           \
    int tn_ = (c_) >> 1, kcn_ = ((c_) & 1) << 7;                              \
    const u16* bs_ = esplit + (size_t)(tn_ * NT) * C_DIM + kcn_;              \
    _Pragma("unroll")                                                         \
    for (int p_ = 0; p_ < 2; ++p_) {                                          \
      int o_ = (w * 2 + p_) * 64 + l;                                         \
      int g2_ = o_ >> 9, rr_ = (o_ >> 3) & 63, p3_ = o_ & 7;                  \
      g2l16(bs_ + (size_t)rr_ * C_DIM + g2_ * 64 + ((p3_ ^ (rr_ & 7)) << 3),  \
            &el[nb_][(w * 2 + p_) * 512]);                                    \
    }                                                                         \
  }

  // prologue: chunk 0 -> buf 0; barrier drains DMA + LDS init
  STAGE_E(0, 0)
  __syncthreads();

  int cur = 0;
#pragma unroll 1
  for (int pass = 0; pass < 2; ++pass) {
#pragma unroll 1
    for (int tile = 0; tile < NTILES; ++tile) {
      int ne0 = ns * SPLITC + tile * NT;
      f32x4 acc[2][4];
#pragma unroll
      for (int rf = 0; rf < 2; ++rf)
#pragma unroll
        for (int cf = 0; cf < 4; ++cf) acc[rf][cf] = vzero;

#pragma unroll
      for (int half = 0; half < 2; ++half) {
        int c = tile * 2 + half;
        if (!(pass == 1 && c == NCHUNK - 1)) STAGE_E(cur ^ 1, (c + 1) & (NCHUNK - 1))
#pragma unroll
        for (int kf = 0; kf < 4; ++kf) {
          int g2 = kf >> 1, ks = kf & 1;
          int phys = (((ks * 4 + hi) ^ (l & 7)) << 3);
#pragma unroll
          for (int cf = 0; cf < 4; ++cf) {
            bf16x8 bfr = *(const bf16x8*)(&el[cur][g2 * 4096 +
                           (cf * 16 + x) * 64 + phys]);
            acc[0][cf] = __builtin_amdgcn_mfma_f32_16x16x32_bf16(A[0][half * 4 + kf], bfr, acc[0][cf], 0, 0, 0);
            acc[1][cf] = __builtin_amdgcn_mfma_f32_16x16x32_bf16(A[1][half * 4 + kf], bfr, acc[1][cf], 0, 0, 0);
          }
        }
        __syncthreads();   // drains next-chunk DMA + this buffer's reads
        cur ^= 1;
      }
      // per-tile epilogue (registers + L2-hot e2 reads only)
      float e2s[4];
#pragma unroll
      for (int cf = 0; cf < 4; ++cf)
        e2s[cf] = e2g[ne0 + cf * 16 + x];
      if (pass == 0) {
#pragma unroll
        for (int rf = 0; rf < 2; ++rf)
#pragma unroll
          for (int r = 0; r < 4; ++r) {
            float z2v = z2r[rf][r];
            float mn = mpl[rf][r];
#pragma unroll
            for (int cf = 0; cf < 4; ++cf)
              mn = fminf(mn, fmaf(-2.f, acc[rf][cf][r], z2v + e2s[cf]));
            mpl[rf][r] = mn;
          }
      } else {
#pragma unroll
        for (int rf = 0; rf < 2; ++rf)
#pragma unroll
          for (int r = 0; r < 4; ++r) {
            int rowl = w * 32 + rf * 16 + hi * 4 + r;
            float z2v = z2r[rf][r];
            float thr = mpl[rf][r];
#pragma unroll
            for (int cf = 0; cf < 4; ++cf) {
              float s = fmaf(-2.f, acc[rf][cf][r], z2v + e2s[cf]);
              if (s <= thr) {
                int pos = atomicAdd(&rcnt[rowl], 1);
                if (pos < CK)
                  rcol[rowl * CK + pos] = (u16)(ne0 + cf * 16 + x);
              }
            }
          }
      }
    }
    if (pass == 0) {
      // one cross-lane reduce + atomicMin (float bits; all s > 0)
#pragma unroll
      for (int rf = 0; rf < 2; ++rf)
#pragma unroll
        for (int r = 0; r < 4; ++r) {
          float mn = mpl[rf][r];
#pragma unroll
          for (int m = 1; m <= 8; m <<= 1)
            mn = fminf(mn, __shfl_xor(mn, m, 64));
          if (x == 0) {
            int rowl = w * 32 + rf * 16 + hi * 4 + r;
            atomicMin(&mrow[rowl], __float_as_uint(mn));
          }
        }
      __syncthreads();
#pragma unroll
      for (int rf = 0; rf < 2; ++rf)
#pragma unroll
        for (int r = 0; r < 4; ++r) {
          int rowl = w * 32 + rf * 16 + hi * 4 + r;
          mpl[rf][r] = __uint_as_float(mrow[rowl]) + EPS;
        }
    }
  }
  __syncthreads();

  // exact rescreen: 2 threads per row, strided over that row's candidates
  {
    int row = t >> 1;
    int cnt = rcnt[row];
    float b = INFINITY; int bi = N_EMB;
    if (cnt <= CK) {
      const float* zr = zt + (size_t)(n0z + row) * C_DIM;
      float z2v = z2g[n0z + row];
      for (int p2 = (t & 1); p2 < cnt; p2 += 2) {
        int col = rcol[row * CK + p2];
        float s = exact_score(zr, emb + (size_t)col * C_DIM, z2v, e2g[col]);
        if (s < b || (s == b && col < bi)) { b = s; bi = col; }
      }
      float ob = __shfl_xor(b, 1, 64);
      int oi2 = __shfl_xor(bi, 1, 64);
      if (ob < b || (ob == b && oi2 < bi)) { b = ob; bi = oi2; }
      if ((t & 1) == 0) {
        cd[ns * N_Z + n0z + row] = b;
        ci[ns * N_Z + n0z + row] = bi;
      }
    }
  }

  // overflow fallback: exact scan of the full split for any overflowed row
  if (t < MBLK && rcnt[t] > CK) {
    int p = atomicAdd(&novf, 1);
    if (p < 32) ovfr[p] = t;
  }
  __syncthreads();
  int no = min(novf, 32);
  for (int oi = 0; oi < no; ++oi) {
    int row = ovfr[oi];
    const float* zr = zt + (size_t)(n0z + row) * C_DIM;
    float z2v = z2g[n0z + row];
    float b = INFINITY; int bi = N_EMB;
#pragma unroll
    for (int q = 0; q < 2; ++q) {
      int col = ns * SPLITC + t * 2 + q;
      float s = exact_score(zr, emb + (size_t)col * C_DIM, z2v, e2g[col]);
      if (s < b || (s == b && col < bi)) { b = s; bi = col; }
    }
#pragma unroll
    for (int m = 1; m <= 32; m <<= 1) {
      float ob = __shfl_xor(b, m, 64);
      int oi2 = __shfl_xor(bi, m, 64);
      if (ob < b || (ob == b && oi2 < bi)) { b = ob; bi = oi2; }
    }
    if (l == 0) { wbs[w] = b; wis[w] = bi; }
    __syncthreads();
    if (t == 0) {
      for (int w2 = 1; w2 < 8; ++w2)
        if (wbs[w2] < b || (wbs[w2] == b && wis[w2] < bi)) { b = wbs[w2]; bi = wis[w2]; }
      cd[ns * N_Z + n0z + row] = b;
      ci[ns * N_Z + n0z + row] = bi;
    }
    __syncthreads();
  }
}

// merge NSPLIT candidates per row, write indices (as float) and gather z_q
__global__ void vq_out(const float* __restrict__ emb, const float* __restrict__ cd,
                       const int* __restrict__ ci, float* __restrict__ out) {
  __shared__ int sidx[32];
  int t = threadIdx.x;
  int n0 = blockIdx.x * 32;
  if (t < 32) {
    int n = n0 + t;
    float b = INFINITY;
    int bi = 0;
    for (int ns = 0; ns < NSPLIT; ++ns) {        // ascending split = ascending idx
      float d = cd[ns * N_Z + n];
      int i = ci[ns * N_Z + n];
      if (d < b || (d == b && i < bi)) { b = d; bi = i; }
    }
    sidx[t] = bi;
    out[ZQ_ELEMS + n] = (float)bi;
  }
  __syncthreads();
  int bb = n0 >> 10, hw0 = n0 & 1023;
  int nl = t & 31, cg = t >> 5;
#pragma unroll
  for (int p = 0; p < 8; ++p) {
    int c0 = cg * 4 + p * 32;
    float4 v = *(const float4*)(emb + (size_t)sidx[nl] * C_DIM + c0);
    out[((size_t)bb * C_DIM + c0 + 0) * HWB + hw0 + nl] = v.x;
    out[((size_t)bb * C_DIM + c0 + 1) * HWB + hw0 + nl] = v.y;
    out[((size_t)bb * C_DIM + c0 + 2) * HWB + hw0 + nl] = v.z;
    out[((size_t)bb * C_DIM + c0 + 3) * HWB + hw0 + nl] = v.w;
  }
}

extern "C" void kernel_launch(void* const* d_in, const int* in_sizes, int n_in,
                              void* d_out, int out_size, void* d_ws, size_t ws_size,
                              hipStream_t stream) {
  const float* hid = (const float*)d_in[0];
  const float* emb = (const float*)d_in[1];
  float* out = (float*)d_out;

  float* zt = (float*)d_ws;                        // 8 MB
  float* z2 = zt + (size_t)N_Z * C_DIM;            // 8192
  float* e2 = z2 + N_Z;                            // 8192
  float* cd = e2 + N_EMB;                          // NSPLIT*8192
  int* ci = (int*)(cd + (size_t)NSPLIT * N_Z);     // NSPLIT*8192
  u16* zbf = (u16*)(ci + (size_t)NSPLIT * N_Z);    // 4 MB
  u16* ebf = zbf + (size_t)N_Z * C_DIM;            // 4 MB

  vq_tr<<<2048, 256, 0, stream>>>(hid, zt, zbf);
  vq_norms<<<64, 256, 0, stream>>>(zt, emb, z2, e2, ebf);
  vq_filter<<<(N_Z / MBLK) * NSPLIT, 512, 0, stream>>>(zbf, ebf, zt, emb, z2, e2, cd, ci);
  vq_out<<<N_Z / 32, 256, 0, stream>>>(emb, cd, ci, out);
}